// Round 5
// baseline (182.223 us; speedup 1.0000x reference)
//
#include <hip/hip_runtime.h>

#define TT    2048
#define SS    512
#define NB    16
#define EPEN  0.60653065971263342f   // exp(-0.5)
#define NCHUNK 64
#define CLEN   32

typedef __attribute__((ext_vector_type(4))) float  floatx4;
typedef __attribute__((ext_vector_type(8))) short  bf16x8;

__device__ __forceinline__ ushort f2bf(float x) {   // RNE fp32 -> bf16
  unsigned u = __float_as_uint(x);
  u += 0x7fffu + ((u >> 16) & 1u);
  return (ushort)(u >> 16);
}

// ---------------- kernel 0: W -> transposed bf16  Wt[col][k] ---------------
__global__ __launch_bounds__(256) void prep_kernel(
    const float* __restrict__ Wa, const float* __restrict__ Ws,
    const float* __restrict__ Wst, ushort* __restrict__ Wt)
{
  int idx = blockIdx.x * 256 + threadIdx.x;       // 336*512 = 172032
  if (idx >= 336 * 512) return;
  int col = idx >> 9, k = idx & 511;
  float v;
  if (col < 288)      v = Wa [(size_t)k * 288 + col];
  else if (col < 320) v = Ws [(size_t)k * 32  + (col - 288)];
  else                v = Wst[(size_t)k * 16  + (col - 320)];
  Wt[idx] = f2bf(v);
}

// ---------------- kernel A: MFMA GEMM (no LDS staging) + softmax -> coef ---
__global__ __launch_bounds__(256) void proj_kernel(
    const float* __restrict__ s_i,
    const ushort* __restrict__ Wt,
    const int*   __restrict__ actions,
    float4*      __restrict__ coef)
{
  __shared__ float lg[32][344];

  const int tid  = threadIdx.x;
  const int wave = tid >> 6, lane = tid & 63;
  const int q = lane >> 4, rc = lane & 15;
  const int row0 = blockIdx.x * 32;

  const int mbase  = (wave >> 1) * 16;
  const int ntile0 = (wave & 1) * 11;
  const int ntiles = (wave & 1) ? 10 : 11;

  int arow = row0 + mbase + rc; if (arow > TT) arow = TT;
  const float*  aptr  = s_i + (size_t)arow * SS + q * 8;
  const ushort* bbase = Wt + (size_t)(ntile0 * 16 + rc) * 512 + q * 8;

  floatx4 acc[11];
  #pragma unroll
  for (int n = 0; n < 11; ++n) acc[n] = (floatx4)(0.f);

  #pragma unroll 2
  for (int kt = 0; kt < 16; ++kt) {
    float4 a0 = *(const float4*)(aptr + kt * 32);
    float4 a1 = *(const float4*)(aptr + kt * 32 + 4);
    bf16x8 af;
    af[0] = (short)f2bf(a0.x); af[1] = (short)f2bf(a0.y);
    af[2] = (short)f2bf(a0.z); af[3] = (short)f2bf(a0.w);
    af[4] = (short)f2bf(a1.x); af[5] = (short)f2bf(a1.y);
    af[6] = (short)f2bf(a1.z); af[7] = (short)f2bf(a1.w);
    #pragma unroll
    for (int n = 0; n < 11; ++n) {
      if (n < ntiles) {
        bf16x8 bf = *(const bf16x8*)(bbase + (size_t)n * 16 * 512 + kt * 32);
        acc[n] = __builtin_amdgcn_mfma_f32_16x16x32_bf16(af, bf, acc[n], 0, 0, 0);
      }
    }
  }

  #pragma unroll
  for (int n = 0; n < 11; ++n) {
    if (n < ntiles) {
      int colt = ntile0 + n;
      #pragma unroll
      for (int reg = 0; reg < 4; ++reg)
        lg[mbase + q * 4 + reg][colt * 16 + rc] = acc[n][reg];
    }
  }
  __syncthreads();

  #pragma unroll
  for (int h = 0; h < 2; ++h) {
    const int r = h * 16 + (tid >> 4), b = tid & 15;
    const int row = row0 + r;
    if (row < TT) {
      float m = -3.4e38f;
      #pragma unroll
      for (int a = 0; a < 18; ++a) m = fmaxf(m, lg[r][b * 18 + a]);
      float sum = 0.f;
      #pragma unroll
      for (int a = 0; a < 18; ++a) sum += __expf(lg[r][b * 18 + a] - m);
      int act = actions[row];
      float aprob = __expf(lg[r][b * 18 + act] - m) / sum;

      float x0 = lg[r][288 + 2 * b], x1 = lg[r][288 + 2 * b + 1];
      float mm = fmaxf(x0, x1);
      float e0 = __expf(x0 - mm), e1 = __expf(x1 - mm);
      float inv = 1.f / (e0 + e1);

      float ms = -3.4e38f;
      #pragma unroll
      for (int j = 0; j < 16; ++j) ms = fmaxf(ms, lg[r][320 + j]);
      float ssum = 0.f;
      #pragma unroll
      for (int j = 0; j < 16; ++j) ssum += __expf(lg[r][320 + j] - ms);
      float stp = __expf(lg[r][320 + b] - ms) / ssum;

      coef[(size_t)row * NB + b] = make_float4(e0 * inv, e1 * inv, stp, aprob);
    } else if (row == TT) {
      float x0 = lg[r][288 + 2 * b], x1 = lg[r][288 + 2 * b + 1];
      float mm = fmaxf(x0, x1);
      float e0 = __expf(x0 - mm), e1 = __expf(x1 - mm);
      coef[(size_t)TT * NB + b] = make_float4(1.f, 0.f, 0.f, e0 / (e0 + e1));
    }
  }
}

// ---------------- kernel B: fused pass1 + walk + terms (single block) ------
template <int N>
__device__ __forceinline__ float ror_add(float v) {
  int r = __builtin_amdgcn_mov_dpp(__float_as_int(v), 0x120 + N, 0xF, 0xF, true);
  return v + __int_as_float(r);
}
__device__ __forceinline__ float reduce16(float v) {
  v = ror_add<8>(v); v = ror_add<4>(v); v = ror_add<2>(v); v = ror_add<1>(v);
  return v;
}

__global__ __launch_bounds__(512) void scan_fused(
    const float4* __restrict__ coef,
    float* __restrict__ Wws, float* __restrict__ Mws,
    float* __restrict__ out)
{
  __shared__ float pk[NCHUNK][16];
  __shared__ int   Ee[NCHUNK];
  __shared__ float racc[33];
  __shared__ int   kacc[32];

  const int tid = threadIdx.x;
  const int gg = tid >> 4;      // 0..31 group
  const int c  = tid & 15;

  // ---- phase 1: build chunk transfer matrices + w-vectors (FIXED prefetch)
  // step J of chunk k uses coef row i0+J  (i0 = k*32+1); rows i0..i0+31.
  for (int h = 0; h < 2; ++h) {
    const int k = gg * 2 + h;
    const int i0 = k * CLEN + 1;
    float G[16];
    #pragma unroll
    for (int r = 0; r < 16; ++r) G[r] = (r == c) ? 1.f : 0.f;
    float4 cfA[16], cfB[16];
    #pragma unroll
    for (int r = 0; r < 16; ++r) cfA[r] = coef[(size_t)i0 * 16 + r];
    #pragma unroll
    for (int r = 0; r < 16; ++r) cfB[r] = coef[(size_t)(i0 + 1) * 16 + r];

#define P1STEP(CF, J)                                                        \
    {                                                                        \
      float ta = 0.f, tb = 0.f, tc2 = 0.f, td = 0.f;                         \
      _Pragma("unroll")                                                      \
      for (int r = 0; r < 4; ++r) {                                          \
        ta  = fmaf(CF[r].y,      G[r],      ta);                             \
        tb  = fmaf(CF[r + 4].y,  G[r + 4],  tb);                             \
        tc2 = fmaf(CF[r + 8].y,  G[r + 8],  tc2);                            \
        td  = fmaf(CF[r + 12].y, G[r + 12], td);                             \
      }                                                                      \
      float et = EPEN * ((ta + tb) + (tc2 + td));                            \
      _Pragma("unroll")                                                      \
      for (int r = 0; r < 16; ++r)                                           \
        G[r] = fmaf(CF[r].x, G[r], CF[r].z * et);                            \
      float wa = 0.f, wb = 0.f, wc2 = 0.f, wd = 0.f;                         \
      _Pragma("unroll")                                                      \
      for (int r = 0; r < 4; ++r) {                                          \
        wa  = fmaf(CF[r].w,      G[r],      wa);                             \
        wb  = fmaf(CF[r + 4].w,  G[r + 4],  wb);                             \
        wc2 = fmaf(CF[r + 8].w,  G[r + 8],  wc2);                            \
        wd  = fmaf(CF[r + 12].w, G[r + 12], wd);                             \
      }                                                                      \
      Wws[(size_t)(k * CLEN + (J)) * 16 + c] = (wa + wb) + (wc2 + wd);       \
    }

    for (int j = 0; j < CLEN; j += 2) {
      P1STEP(cfA, j);                         // uses row i0+j   (correct)
      if (j + 2 < CLEN) {
        #pragma unroll
        for (int r = 0; r < 16; ++r) cfA[r] = coef[(size_t)(i0 + j + 2) * 16 + r];
      }
      P1STEP(cfB, j + 1);                     // uses row i0+j+1 (correct)
      if (j + 3 < CLEN) {
        #pragma unroll
        for (int r = 0; r < 16; ++r) cfB[r] = coef[(size_t)(i0 + j + 3) * 16 + r];
      }
    }
#undef P1STEP

    // column-major store for the walk: Mws[k*256 + c*16 + r] = M_k[r][c]
    #pragma unroll
    for (int rr = 0; rr < 4; ++rr) {
      float4 v = make_float4(G[rr * 4], G[rr * 4 + 1], G[rr * 4 + 2], G[rr * 4 + 3]);
      *(float4*)(Mws + k * 256 + c * 16 + rr * 4) = v;
    }
  }
  __syncthreads();

  // ---- phase 2: wave-0 sequential chunk walk ----
  if (tid < 64) {
    const int g = tid >> 4, cw = tid & 15;
    float4 c0 = coef[cw];
    float p = c0.z;
    float U0 = reduce16(c0.w * p);
    if (tid == 0) { racc[32] = __logf(U0); Ee[0] = 0; }
    if (g == 0) pk[0][cw] = p;
    int Ecum = 0;

    float4 mcur  = *(const float4*)(Mws + 0 * 256 + cw * 16 + g * 4);
    float4 mnext = *(const float4*)(Mws + 1 * 256 + cw * 16 + g * 4);
    for (int k = 0; k < NCHUNK; ++k) {
      float4 mc = mcur; mcur = mnext;
      if (k + 2 < NCHUNK)
        mnext = *(const float4*)(Mws + (size_t)(k + 2) * 256 + cw * 16 + g * 4);
      float y0 = reduce16(mc.x * p);
      float y1 = reduce16(mc.y * p);
      float y2 = reduce16(mc.z * p);
      float y3 = reduce16(mc.w * p);
      int sel = cw & 3;
      float z = (sel == 0) ? y0 : (sel == 1) ? y1 : (sel == 2) ? y2 : y3;
      int src = (((cw >> 2) * 16 + cw) << 2);
      float pn = __int_as_float(
          __builtin_amdgcn_ds_bpermute(src, __float_as_int(z)));
      int bits = __builtin_amdgcn_readfirstlane(__float_as_int(pn));
      int eb = (bits >> 23) & 255;
      Ecum += eb - 127;
      p = pn * __int_as_float((254 - eb) << 23);   // * 2^{-(eb-127)}, exact
      if (k + 1 < NCHUNK) {
        if (g == 0) pk[k + 1][cw] = p;
        if (tid == 0) Ee[k + 1] = Ecum;
      }
    }
  }
  __syncthreads();

  // ---- phase 3: parallel term dot-products (32 groups x 64 steps) ----
  float acc = 0.f;
  int klocal = 0;
  #pragma unroll
  for (int h = 0; h < 2; ++h) {
    const int k = gg * 2 + h;
    const float pc = pk[k][c];
    klocal += CLEN * Ee[k];
    #pragma unroll
    for (int j = 0; j < CLEN; ++j) {
      float w = Wws[(size_t)(k * CLEN + j) * 16 + c];
      float U = reduce16(w * pc);
      acc += __logf(U);
    }
  }
  if (c == 0) { racc[gg] = acc; kacc[gg] = klocal; }
  __syncthreads();
  if (tid == 0) {
    double s = (double)racc[32];
    long long K = 0;
    for (int i = 0; i < 32; ++i) { s += (double)racc[i]; K += (long long)kacc[i]; }
    out[0] = (float)(s + 0.6931471805599453 * (double)K);
  }
}

extern "C" void kernel_launch(void* const* d_in, const int* in_sizes, int n_in,
                              void* d_out, int out_size, void* d_ws, size_t ws_size,
                              hipStream_t stream) {
  const float* s_i = (const float*)d_in[0];
  const float* Wa  = (const float*)d_in[1];
  const float* Ws  = (const float*)d_in[2];
  const float* Wst = (const float*)d_in[3];
  const int*   act = (const int*)d_in[4];

  char* ws = (char*)d_ws;
  float4* coef = (float4*)ws;                        //   524,544 B
  float*  Wws  = (float*)(ws + 524544);              // + 131,072 B
  float*  Mws  = (float*)(ws + 524544 + 131072);     // +  65,536 B
  ushort* Wt   = (ushort*)(ws + 524544 + 131072 + 65536);  // + 344,064 B

  prep_kernel<<<672, 256, 0, stream>>>(Wa, Ws, Wst, Wt);
  proj_kernel<<<65,  256, 0, stream>>>(s_i, Wt, act, coef);
  scan_fused <<<1,   512, 0, stream>>>(coef, Wws, Mws, (float*)d_out);
}

// Round 6
// 153.715 us; speedup vs baseline: 1.1855x; 1.1855x over previous
//
#include <hip/hip_runtime.h>

#define TT    2048
#define SS    512
#define NB    16
#define EPEN  0.60653065971263342f   // exp(-0.5)
#define NCHUNK 64
#define CLEN   32
#define NBLK  65
#define MAGIC 0x5ca1ab1e

typedef __attribute__((ext_vector_type(4))) float  floatx4;
typedef __attribute__((ext_vector_type(8))) short  bf16x8;

__device__ __forceinline__ ushort f2bf(float x) {   // RNE fp32 -> bf16
  unsigned u = __float_as_uint(x);
  u += 0x7fffu + ((u >> 16) & 1u);
  return (ushort)(u >> 16);
}

template <int N>
__device__ __forceinline__ float ror_add(float v) {
  int r = __builtin_amdgcn_mov_dpp(__float_as_int(v), 0x120 + N, 0xF, 0xF, true);
  return v + __int_as_float(r);
}
__device__ __forceinline__ float reduce16(float v) {
  v = ror_add<8>(v); v = ror_add<4>(v); v = ror_add<2>(v); v = ror_add<1>(v);
  return v;
}

__device__ __forceinline__ void grid_barrier(int* bar, int idx) {
  __syncthreads();
  if (threadIdx.x == 0) {
    __hip_atomic_fetch_add(&bar[idx], 1, __ATOMIC_ACQ_REL, __HIP_MEMORY_SCOPE_AGENT);
    while (__hip_atomic_load(&bar[idx], __ATOMIC_ACQUIRE, __HIP_MEMORY_SCOPE_AGENT) < NBLK)
      __builtin_amdgcn_s_sleep(1);
  }
  __syncthreads();
}

__global__ __launch_bounds__(256, 1) void fused_all(
    const float* __restrict__ s_i,
    const float* __restrict__ Wa,
    const float* __restrict__ Ws,
    const float* __restrict__ Wst,
    const int*   __restrict__ actions,
    float4* __restrict__ coef, float* __restrict__ Wws,
    float* __restrict__ Mws,   ushort* __restrict__ Wt,
    int* __restrict__ bar,     float* __restrict__ out)
{
  __shared__ float lg[32][344];            // proj logits (44 KB)
  __shared__ float pk[NCHUNK][16];
  __shared__ int   Ee[NCHUNK];
  __shared__ float racc[17];
  __shared__ int   kacc[16];

  const int tid = threadIdx.x;
  const int bid = blockIdx.x;

  // ---- init: block 0 zeroes barrier counters, publishes MAGIC ----
  if (bid == 0 && tid == 0) {
    #pragma unroll
    for (int i = 0; i < 4; ++i)
      __hip_atomic_store(&bar[i], 0, __ATOMIC_RELAXED, __HIP_MEMORY_SCOPE_AGENT);
    __hip_atomic_store(&bar[7], MAGIC, __ATOMIC_RELEASE, __HIP_MEMORY_SCOPE_AGENT);
  }

  // ---- phase A: W -> transposed bf16 Wt[col][k], 8-k strips ----
  for (int sid = bid * 256 + tid; sid < 336 * 64; sid += NBLK * 256) {
    int col = sid >> 6, kk = (sid & 63) << 3;
    const float* src; int ld, cc;
    if (col < 288)      { src = Wa;  ld = 288; cc = col; }
    else if (col < 320) { src = Ws;  ld = 32;  cc = col - 288; }
    else                { src = Wst; ld = 16;  cc = col - 320; }
    uint4 pkd;
    uint h0 = f2bf(src[(size_t)(kk+0)*ld+cc]) | ((uint)f2bf(src[(size_t)(kk+1)*ld+cc]) << 16);
    uint h1 = f2bf(src[(size_t)(kk+2)*ld+cc]) | ((uint)f2bf(src[(size_t)(kk+3)*ld+cc]) << 16);
    uint h2 = f2bf(src[(size_t)(kk+4)*ld+cc]) | ((uint)f2bf(src[(size_t)(kk+5)*ld+cc]) << 16);
    uint h3 = f2bf(src[(size_t)(kk+6)*ld+cc]) | ((uint)f2bf(src[(size_t)(kk+7)*ld+cc]) << 16);
    pkd.x = h0; pkd.y = h1; pkd.z = h2; pkd.w = h3;
    *(uint4*)(Wt + (size_t)col * 512 + kk) = pkd;
  }

  // wait for init handshake, then barrier 0 (Wt ready)
  if (tid == 0)
    while (__hip_atomic_load(&bar[7], __ATOMIC_ACQUIRE, __HIP_MEMORY_SCOPE_AGENT) != MAGIC)
      __builtin_amdgcn_s_sleep(1);
  grid_barrier(bar, 0);

  // ---- phase B: MFMA proj + softmax -> coef (32 rows/block) ----
  {
    const int wave = tid >> 6, lane = tid & 63;
    const int q = lane >> 4, rc = lane & 15;
    const int row0 = bid * 32;
    const int mbase  = (wave >> 1) * 16;
    const int ntile0 = (wave & 1) * 11;
    const int ntiles = (wave & 1) ? 10 : 11;

    int arow = row0 + mbase + rc; if (arow > TT) arow = TT;
    const float*  aptr  = s_i + (size_t)arow * SS + q * 8;
    const ushort* bbase = Wt + (size_t)(ntile0 * 16 + rc) * 512 + q * 8;

    floatx4 acc[11];
    #pragma unroll
    for (int n = 0; n < 11; ++n) acc[n] = (floatx4)(0.f);

    #pragma unroll 2
    for (int kt = 0; kt < 16; ++kt) {
      float4 a0 = *(const float4*)(aptr + kt * 32);
      float4 a1 = *(const float4*)(aptr + kt * 32 + 4);
      bf16x8 af;
      af[0] = (short)f2bf(a0.x); af[1] = (short)f2bf(a0.y);
      af[2] = (short)f2bf(a0.z); af[3] = (short)f2bf(a0.w);
      af[4] = (short)f2bf(a1.x); af[5] = (short)f2bf(a1.y);
      af[6] = (short)f2bf(a1.z); af[7] = (short)f2bf(a1.w);
      #pragma unroll
      for (int n = 0; n < 11; ++n) {
        if (n < ntiles) {
          bf16x8 bf = *(const bf16x8*)(bbase + (size_t)n * 16 * 512 + kt * 32);
          acc[n] = __builtin_amdgcn_mfma_f32_16x16x32_bf16(af, bf, acc[n], 0, 0, 0);
        }
      }
    }

    #pragma unroll
    for (int n = 0; n < 11; ++n) {
      if (n < ntiles) {
        int colt = ntile0 + n;
        #pragma unroll
        for (int reg = 0; reg < 4; ++reg)
          lg[mbase + q * 4 + reg][colt * 16 + rc] = acc[n][reg];
      }
    }
    __syncthreads();

    #pragma unroll
    for (int h = 0; h < 2; ++h) {
      const int r = h * 16 + (tid >> 4), b = tid & 15;
      const int row = row0 + r;
      if (row < TT) {
        float m = -3.4e38f;
        #pragma unroll
        for (int a = 0; a < 18; ++a) m = fmaxf(m, lg[r][b * 18 + a]);
        float sum = 0.f;
        #pragma unroll
        for (int a = 0; a < 18; ++a) sum += __expf(lg[r][b * 18 + a] - m);
        int act = actions[row];
        float aprob = __expf(lg[r][b * 18 + act] - m) / sum;

        float x0 = lg[r][288 + 2 * b], x1 = lg[r][288 + 2 * b + 1];
        float mm = fmaxf(x0, x1);
        float e0 = __expf(x0 - mm), e1 = __expf(x1 - mm);
        float inv = 1.f / (e0 + e1);

        float ms = -3.4e38f;
        #pragma unroll
        for (int j = 0; j < 16; ++j) ms = fmaxf(ms, lg[r][320 + j]);
        float ssum = 0.f;
        #pragma unroll
        for (int j = 0; j < 16; ++j) ssum += __expf(lg[r][320 + j] - ms);
        float stp = __expf(lg[r][320 + b] - ms) / ssum;

        coef[(size_t)row * NB + b] = make_float4(e0 * inv, e1 * inv, stp, aprob);
      } else if (row == TT) {
        float x0 = lg[r][288 + 2 * b], x1 = lg[r][288 + 2 * b + 1];
        float mm = fmaxf(x0, x1);
        float e0 = __expf(x0 - mm), e1 = __expf(x1 - mm);
        coef[(size_t)TT * NB + b] = make_float4(1.f, 0.f, 0.f, e0 / (e0 + e1));
      }
    }
  }
  grid_barrier(bar, 1);   // coef ready

  // ---- phase C: pass1 (blocks 0..15, 4 chunks each, FIXED prefetch) ----
  if (bid < 16 && tid < 64) {
    const int k = bid * 4 + (tid >> 4);
    const int c = tid & 15;
    const int i0 = k * CLEN + 1;
    float G[16];
    #pragma unroll
    for (int r = 0; r < 16; ++r) G[r] = (r == c) ? 1.f : 0.f;
    float4 cfA[16], cfB[16];
    #pragma unroll
    for (int r = 0; r < 16; ++r) cfA[r] = coef[(size_t)i0 * 16 + r];
    #pragma unroll
    for (int r = 0; r < 16; ++r) cfB[r] = coef[(size_t)(i0 + 1) * 16 + r];

#define P1STEP(CF, J)                                                        \
    {                                                                        \
      float ta = 0.f, tb = 0.f, tc2 = 0.f, td = 0.f;                         \
      _Pragma("unroll")                                                      \
      for (int r = 0; r < 4; ++r) {                                          \
        ta  = fmaf(CF[r].y,      G[r],      ta);                             \
        tb  = fmaf(CF[r + 4].y,  G[r + 4],  tb);                             \
        tc2 = fmaf(CF[r + 8].y,  G[r + 8],  tc2);                            \
        td  = fmaf(CF[r + 12].y, G[r + 12], td);                             \
      }                                                                      \
      float et = EPEN * ((ta + tb) + (tc2 + td));                            \
      _Pragma("unroll")                                                      \
      for (int r = 0; r < 16; ++r)                                           \
        G[r] = fmaf(CF[r].x, G[r], CF[r].z * et);                            \
      float wa = 0.f, wb = 0.f, wc2 = 0.f, wd = 0.f;                         \
      _Pragma("unroll")                                                      \
      for (int r = 0; r < 4; ++r) {                                          \
        wa  = fmaf(CF[r].w,      G[r],      wa);                             \
        wb  = fmaf(CF[r + 4].w,  G[r + 4],  wb);                             \
        wc2 = fmaf(CF[r + 8].w,  G[r + 8],  wc2);                            \
        wd  = fmaf(CF[r + 12].w, G[r + 12], wd);                             \
      }                                                                      \
      Wws[(size_t)(k * CLEN + (J)) * 16 + c] = (wa + wb) + (wc2 + wd);       \
    }

    for (int j = 0; j < CLEN; j += 2) {
      P1STEP(cfA, j);                         // uses row i0+j
      if (j + 2 < CLEN) {
        #pragma unroll
        for (int r = 0; r < 16; ++r) cfA[r] = coef[(size_t)(i0 + j + 2) * 16 + r];
      }
      P1STEP(cfB, j + 1);                     // uses row i0+j+1
      if (j + 3 < CLEN) {
        #pragma unroll
        for (int r = 0; r < 16; ++r) cfB[r] = coef[(size_t)(i0 + j + 3) * 16 + r];
      }
    }
#undef P1STEP

    #pragma unroll
    for (int rr = 0; rr < 4; ++rr) {
      float4 v = make_float4(G[rr * 4], G[rr * 4 + 1], G[rr * 4 + 2], G[rr * 4 + 3]);
      *(float4*)(Mws + k * 256 + c * 16 + rr * 4) = v;   // col-major per chunk
    }
  }
  grid_barrier(bar, 2);   // Wws/Mws ready

  if (bid != 0) return;

  // ---- phase D (block 0 only): 1-wave chunk walk ----
  if (tid < 64) {
    const int g = tid >> 4, cw = tid & 15;
    float4 c0 = coef[cw];
    float p = c0.z;
    float U0 = reduce16(c0.w * p);
    if (tid == 0) { racc[16] = __logf(U0); Ee[0] = 0; }
    if (g == 0) pk[0][cw] = p;
    int Ecum = 0;

    float4 mcur  = *(const float4*)(Mws + 0 * 256 + cw * 16 + g * 4);
    float4 mnext = *(const float4*)(Mws + 1 * 256 + cw * 16 + g * 4);
    for (int k = 0; k < NCHUNK; ++k) {
      float4 mc = mcur; mcur = mnext;
      if (k + 2 < NCHUNK)
        mnext = *(const float4*)(Mws + (size_t)(k + 2) * 256 + cw * 16 + g * 4);
      float y0 = reduce16(mc.x * p);
      float y1 = reduce16(mc.y * p);
      float y2 = reduce16(mc.z * p);
      float y3 = reduce16(mc.w * p);
      int sel = cw & 3;
      float z = (sel == 0) ? y0 : (sel == 1) ? y1 : (sel == 2) ? y2 : y3;
      int src = (((cw >> 2) * 16 + cw) << 2);
      float pn = __int_as_float(
          __builtin_amdgcn_ds_bpermute(src, __float_as_int(z)));
      int bits = __builtin_amdgcn_readfirstlane(__float_as_int(pn));
      int eb = (bits >> 23) & 255;
      Ecum += eb - 127;
      p = pn * __int_as_float((254 - eb) << 23);   // * 2^{-(eb-127)}, exact
      if (k + 1 < NCHUNK) {
        if (g == 0) pk[k + 1][cw] = p;
        if (tid == 0) Ee[k + 1] = Ecum;
      }
    }
  }
  __syncthreads();

  // ---- terms: 16 groups x 4 chunks x 32 steps ----
  {
    const int gg = tid >> 4, c = tid & 15;
    float acc = 0.f;
    int klocal = 0;
    #pragma unroll
    for (int h = 0; h < 4; ++h) {
      const int k = gg * 4 + h;
      const float pc = pk[k][c];
      klocal += CLEN * Ee[k];
      #pragma unroll 8
      for (int j = 0; j < CLEN; ++j) {
        float w = Wws[(size_t)(k * CLEN + j) * 16 + c];
        float U = reduce16(w * pc);
        acc += __logf(U);
      }
    }
    if (c == 0) { racc[gg] = acc; kacc[gg] = klocal; }
  }
  __syncthreads();
  if (tid == 0) {
    double s = (double)racc[16];
    long long K = 0;
    #pragma unroll
    for (int i = 0; i < 16; ++i) { s += (double)racc[i]; K += (long long)kacc[i]; }
    out[0] = (float)(s + 0.6931471805599453 * (double)K);
  }
}

extern "C" void kernel_launch(void* const* d_in, const int* in_sizes, int n_in,
                              void* d_out, int out_size, void* d_ws, size_t ws_size,
                              hipStream_t stream) {
  const float* s_i = (const float*)d_in[0];
  const float* Wa  = (const float*)d_in[1];
  const float* Ws  = (const float*)d_in[2];
  const float* Wst = (const float*)d_in[3];
  const int*   act = (const int*)d_in[4];

  char* ws = (char*)d_ws;
  float4* coef = (float4*)ws;                              //   524,544 B
  float*  Wws  = (float*)(ws + 524544);                    // + 131,072 B
  float*  Mws  = (float*)(ws + 524544 + 131072);           // +  65,536 B
  ushort* Wt   = (ushort*)(ws + 524544 + 131072 + 65536);  // + 344,064 B
  int*    bar  = (int*)(ws + 1065216);                     // barrier counters

  fused_all<<<NBLK, 256, 0, stream>>>(s_i, Wa, Ws, Wst, act,
                                      coef, Wws, Mws, Wt, bar, (float*)d_out);
}

// Round 7
// 148.147 us; speedup vs baseline: 1.2300x; 1.0376x over previous
//
#include <hip/hip_runtime.h>

#define TT    2048
#define SS    512
#define NB    16
#define EPEN  0.60653065971263342f   // exp(-0.5)
#define NCHUNK 64
#define CLEN   32
#define NBLK  65
#define MAGIC 0x5ca1ab1e

typedef __attribute__((ext_vector_type(4))) float  floatx4;
typedef __attribute__((ext_vector_type(8))) short  bf16x8;

__device__ __forceinline__ ushort f2bf(float x) {   // RNE fp32 -> bf16
  unsigned u = __float_as_uint(x);
  u += 0x7fffu + ((u >> 16) & 1u);
  return (ushort)(u >> 16);
}

template <int N>
__device__ __forceinline__ float ror_add(float v) {
  int r = __builtin_amdgcn_mov_dpp(__float_as_int(v), 0x120 + N, 0xF, 0xF, true);
  return v + __int_as_float(r);
}
__device__ __forceinline__ float reduce16(float v) {
  v = ror_add<8>(v); v = ror_add<4>(v); v = ror_add<2>(v); v = ror_add<1>(v);
  return v;
}

// Relaxed-poll barrier: RMW polls hit the coherence point (always fresh, no
// per-iteration cache invalidate); exactly ONE release fence on arrive and
// ONE acquire fence on exit.
__device__ __forceinline__ int poll(int* p) {
  return __hip_atomic_fetch_add(p, 0, __ATOMIC_RELAXED, __HIP_MEMORY_SCOPE_AGENT);
}
__device__ __forceinline__ void grid_barrier(int* bar, int idx) {
  __syncthreads();
  if (threadIdx.x == 0) {
    __builtin_amdgcn_fence(__ATOMIC_RELEASE, "agent");
    __hip_atomic_fetch_add(&bar[idx], 1, __ATOMIC_RELAXED, __HIP_MEMORY_SCOPE_AGENT);
    while (poll(&bar[idx]) < NBLK)
      __builtin_amdgcn_s_sleep(2);
    __builtin_amdgcn_fence(__ATOMIC_ACQUIRE, "agent");
  }
  __syncthreads();
}

__global__ __launch_bounds__(256, 1) void fused_all(
    const float* __restrict__ s_i,
    const float* __restrict__ Wa,
    const float* __restrict__ Ws,
    const float* __restrict__ Wst,
    const int*   __restrict__ actions,
    float4* __restrict__ coef, float* __restrict__ Wws,
    float* __restrict__ Mws,   ushort* __restrict__ Wt,
    int* __restrict__ bar,     float* __restrict__ out)
{
  __shared__ float lg[32][344];            // proj logits (44 KB)
  __shared__ float pk[NCHUNK][16];
  __shared__ int   Ee[NCHUNK];
  __shared__ float racc[17];
  __shared__ int   kacc[16];

  const int tid = threadIdx.x;
  const int bid = blockIdx.x;

  // ---- init: block 0 zeroes barrier counters, publishes MAGIC ----
  if (bid == 0 && tid == 0) {
    #pragma unroll
    for (int i = 0; i < 4; ++i)
      __hip_atomic_store(&bar[i], 0, __ATOMIC_RELAXED, __HIP_MEMORY_SCOPE_AGENT);
    __builtin_amdgcn_fence(__ATOMIC_RELEASE, "agent");
    __hip_atomic_store(&bar[7], MAGIC, __ATOMIC_RELAXED, __HIP_MEMORY_SCOPE_AGENT);
  }

  // ---- phase A: W -> transposed bf16 Wt[col][k], 8-k strips ----
  for (int sid = bid * 256 + tid; sid < 336 * 64; sid += NBLK * 256) {
    int col = sid >> 6, kk = (sid & 63) << 3;
    const float* src; int ld, cc;
    if (col < 288)      { src = Wa;  ld = 288; cc = col; }
    else if (col < 320) { src = Ws;  ld = 32;  cc = col - 288; }
    else                { src = Wst; ld = 16;  cc = col - 320; }
    uint4 pkd;
    uint h0 = f2bf(src[(size_t)(kk+0)*ld+cc]) | ((uint)f2bf(src[(size_t)(kk+1)*ld+cc]) << 16);
    uint h1 = f2bf(src[(size_t)(kk+2)*ld+cc]) | ((uint)f2bf(src[(size_t)(kk+3)*ld+cc]) << 16);
    uint h2 = f2bf(src[(size_t)(kk+4)*ld+cc]) | ((uint)f2bf(src[(size_t)(kk+5)*ld+cc]) << 16);
    uint h3 = f2bf(src[(size_t)(kk+6)*ld+cc]) | ((uint)f2bf(src[(size_t)(kk+7)*ld+cc]) << 16);
    pkd.x = h0; pkd.y = h1; pkd.z = h2; pkd.w = h3;
    *(uint4*)(Wt + (size_t)col * 512 + kk) = pkd;
  }

  // wait for init handshake (relaxed RMW poll + one acquire), then barrier 0
  if (tid == 0) {
    while (poll(&bar[7]) != (int)MAGIC)
      __builtin_amdgcn_s_sleep(2);
    __builtin_amdgcn_fence(__ATOMIC_ACQUIRE, "agent");
  }
  grid_barrier(bar, 0);

  // ---- phase B: MFMA proj + softmax -> coef (32 rows/block) ----
  {
    const int wave = tid >> 6, lane = tid & 63;
    const int q = lane >> 4, rc = lane & 15;
    const int row0 = bid * 32;
    const int mbase  = (wave >> 1) * 16;
    const int ntile0 = (wave & 1) * 11;
    const int ntiles = (wave & 1) ? 10 : 11;

    int arow = row0 + mbase + rc; if (arow > TT) arow = TT;
    const float*  aptr  = s_i + (size_t)arow * SS + q * 8;
    const ushort* bbase = Wt + (size_t)(ntile0 * 16 + rc) * 512 + q * 8;

    floatx4 acc[11];
    #pragma unroll
    for (int n = 0; n < 11; ++n) acc[n] = (floatx4)(0.f);

    #pragma unroll 2
    for (int kt = 0; kt < 16; ++kt) {
      float4 a0 = *(const float4*)(aptr + kt * 32);
      float4 a1 = *(const float4*)(aptr + kt * 32 + 4);
      bf16x8 af;
      af[0] = (short)f2bf(a0.x); af[1] = (short)f2bf(a0.y);
      af[2] = (short)f2bf(a0.z); af[3] = (short)f2bf(a0.w);
      af[4] = (short)f2bf(a1.x); af[5] = (short)f2bf(a1.y);
      af[6] = (short)f2bf(a1.z); af[7] = (short)f2bf(a1.w);
      #pragma unroll
      for (int n = 0; n < 11; ++n) {
        if (n < ntiles) {
          bf16x8 bf = *(const bf16x8*)(bbase + (size_t)n * 16 * 512 + kt * 32);
          acc[n] = __builtin_amdgcn_mfma_f32_16x16x32_bf16(af, bf, acc[n], 0, 0, 0);
        }
      }
    }

    #pragma unroll
    for (int n = 0; n < 11; ++n) {
      if (n < ntiles) {
        int colt = ntile0 + n;
        #pragma unroll
        for (int reg = 0; reg < 4; ++reg)
          lg[mbase + q * 4 + reg][colt * 16 + rc] = acc[n][reg];
      }
    }
    __syncthreads();

    #pragma unroll
    for (int h = 0; h < 2; ++h) {
      const int r = h * 16 + (tid >> 4), b = tid & 15;
      const int row = row0 + r;
      if (row < TT) {
        float m = -3.4e38f;
        #pragma unroll
        for (int a = 0; a < 18; ++a) m = fmaxf(m, lg[r][b * 18 + a]);
        float sum = 0.f;
        #pragma unroll
        for (int a = 0; a < 18; ++a) sum += __expf(lg[r][b * 18 + a] - m);
        int act = actions[row];
        float aprob = __expf(lg[r][b * 18 + act] - m) / sum;

        float x0 = lg[r][288 + 2 * b], x1 = lg[r][288 + 2 * b + 1];
        float mm = fmaxf(x0, x1);
        float e0 = __expf(x0 - mm), e1 = __expf(x1 - mm);
        float inv = 1.f / (e0 + e1);

        float ms = -3.4e38f;
        #pragma unroll
        for (int j = 0; j < 16; ++j) ms = fmaxf(ms, lg[r][320 + j]);
        float ssum = 0.f;
        #pragma unroll
        for (int j = 0; j < 16; ++j) ssum += __expf(lg[r][320 + j] - ms);
        float stp = __expf(lg[r][320 + b] - ms) / ssum;

        coef[(size_t)row * NB + b] = make_float4(e0 * inv, e1 * inv, stp, aprob);
      } else if (row == TT) {
        float x0 = lg[r][288 + 2 * b], x1 = lg[r][288 + 2 * b + 1];
        float mm = fmaxf(x0, x1);
        float e0 = __expf(x0 - mm), e1 = __expf(x1 - mm);
        coef[(size_t)TT * NB + b] = make_float4(1.f, 0.f, 0.f, e0 / (e0 + e1));
      }
    }
  }
  grid_barrier(bar, 1);   // coef ready

  // ---- phase C: pass1 (blocks 0..15, 4 chunks each) ----
  if (bid < 16 && tid < 64) {
    const int k = bid * 4 + (tid >> 4);
    const int c = tid & 15;
    const int i0 = k * CLEN + 1;
    float G[16];
    #pragma unroll
    for (int r = 0; r < 16; ++r) G[r] = (r == c) ? 1.f : 0.f;
    float4 cfA[16], cfB[16];
    #pragma unroll
    for (int r = 0; r < 16; ++r) cfA[r] = coef[(size_t)i0 * 16 + r];
    #pragma unroll
    for (int r = 0; r < 16; ++r) cfB[r] = coef[(size_t)(i0 + 1) * 16 + r];

#define P1STEP(CF, J)                                                        \
    {                                                                        \
      float ta = 0.f, tb = 0.f, tc2 = 0.f, td = 0.f;                         \
      _Pragma("unroll")                                                      \
      for (int r = 0; r < 4; ++r) {                                          \
        ta  = fmaf(CF[r].y,      G[r],      ta);                             \
        tb  = fmaf(CF[r + 4].y,  G[r + 4],  tb);                             \
        tc2 = fmaf(CF[r + 8].y,  G[r + 8],  tc2);                            \
        td  = fmaf(CF[r + 12].y, G[r + 12], td);                             \
      }                                                                      \
      float et = EPEN * ((ta + tb) + (tc2 + td));                            \
      _Pragma("unroll")                                                      \
      for (int r = 0; r < 16; ++r)                                           \
        G[r] = fmaf(CF[r].x, G[r], CF[r].z * et);                            \
      float wa = 0.f, wb = 0.f, wc2 = 0.f, wd = 0.f;                         \
      _Pragma("unroll")                                                      \
      for (int r = 0; r < 4; ++r) {                                          \
        wa  = fmaf(CF[r].w,      G[r],      wa);                             \
        wb  = fmaf(CF[r + 4].w,  G[r + 4],  wb);                             \
        wc2 = fmaf(CF[r + 8].w,  G[r + 8],  wc2);                            \
        wd  = fmaf(CF[r + 12].w, G[r + 12], wd);                             \
      }                                                                      \
      Wws[(size_t)(k * CLEN + (J)) * 16 + c] = (wa + wb) + (wc2 + wd);       \
    }

    for (int j = 0; j < CLEN; j += 2) {
      P1STEP(cfA, j);                         // uses row i0+j
      if (j + 2 < CLEN) {
        #pragma unroll
        for (int r = 0; r < 16; ++r) cfA[r] = coef[(size_t)(i0 + j + 2) * 16 + r];
      }
      P1STEP(cfB, j + 1);                     // uses row i0+j+1
      if (j + 3 < CLEN) {
        #pragma unroll
        for (int r = 0; r < 16; ++r) cfB[r] = coef[(size_t)(i0 + j + 3) * 16 + r];
      }
    }
#undef P1STEP

    #pragma unroll
    for (int rr = 0; rr < 4; ++rr) {
      float4 v = make_float4(G[rr * 4], G[rr * 4 + 1], G[rr * 4 + 2], G[rr * 4 + 3]);
      *(float4*)(Mws + k * 256 + c * 16 + rr * 4) = v;   // col-major per chunk
    }
  }
  grid_barrier(bar, 2);   // Wws/Mws ready

  if (bid != 0) return;

  // ---- phase D (block 0 only): 1-wave chunk walk ----
  if (tid < 64) {
    const int g = tid >> 4, cw = tid & 15;
    float4 c0 = coef[cw];
    float p = c0.z;
    float U0 = reduce16(c0.w * p);
    if (tid == 0) { racc[16] = __logf(U0); Ee[0] = 0; }
    if (g == 0) pk[0][cw] = p;
    int Ecum = 0;

    float4 mcur  = *(const float4*)(Mws + 0 * 256 + cw * 16 + g * 4);
    float4 mnext = *(const float4*)(Mws + 1 * 256 + cw * 16 + g * 4);
    for (int k = 0; k < NCHUNK; ++k) {
      float4 mc = mcur; mcur = mnext;
      if (k + 2 < NCHUNK)
        mnext = *(const float4*)(Mws + (size_t)(k + 2) * 256 + cw * 16 + g * 4);
      float y0 = reduce16(mc.x * p);
      float y1 = reduce16(mc.y * p);
      float y2 = reduce16(mc.z * p);
      float y3 = reduce16(mc.w * p);
      int sel = cw & 3;
      float z = (sel == 0) ? y0 : (sel == 1) ? y1 : (sel == 2) ? y2 : y3;
      int src = (((cw >> 2) * 16 + cw) << 2);
      float pn = __int_as_float(
          __builtin_amdgcn_ds_bpermute(src, __float_as_int(z)));
      int bits = __builtin_amdgcn_readfirstlane(__float_as_int(pn));
      int eb = (bits >> 23) & 255;
      Ecum += eb - 127;
      p = pn * __int_as_float((254 - eb) << 23);   // * 2^{-(eb-127)}, exact
      if (k + 1 < NCHUNK) {
        if (g == 0) pk[k + 1][cw] = p;
        if (tid == 0) Ee[k + 1] = Ecum;
      }
    }
  }
  __syncthreads();

  // ---- terms: 16 groups x 4 chunks x 32 steps ----
  {
    const int gg = tid >> 4, c = tid & 15;
    float acc = 0.f;
    int klocal = 0;
    #pragma unroll
    for (int h = 0; h < 4; ++h) {
      const int k = gg * 4 + h;
      const float pc = pk[k][c];
      klocal += CLEN * Ee[k];
      #pragma unroll 8
      for (int j = 0; j < CLEN; ++j) {
        float w = Wws[(size_t)(k * CLEN + j) * 16 + c];
        float U = reduce16(w * pc);
        acc += __logf(U);
      }
    }
    if (c == 0) { racc[gg] = acc; kacc[gg] = klocal; }
  }
  __syncthreads();
  if (tid == 0) {
    double s = (double)racc[16];
    long long K = 0;
    #pragma unroll
    for (int i = 0; i < 16; ++i) { s += (double)racc[i]; K += (long long)kacc[i]; }
    out[0] = (float)(s + 0.6931471805599453 * (double)K);
  }
}

extern "C" void kernel_launch(void* const* d_in, const int* in_sizes, int n_in,
                              void* d_out, int out_size, void* d_ws, size_t ws_size,
                              hipStream_t stream) {
  const float* s_i = (const float*)d_in[0];
  const float* Wa  = (const float*)d_in[1];
  const float* Ws  = (const float*)d_in[2];
  const float* Wst = (const float*)d_in[3];
  const int*   act = (const int*)d_in[4];

  char* ws = (char*)d_ws;
  float4* coef = (float4*)ws;                              //   524,544 B
  float*  Wws  = (float*)(ws + 524544);                    // + 131,072 B
  float*  Mws  = (float*)(ws + 524544 + 131072);           // +  65,536 B
  ushort* Wt   = (ushort*)(ws + 524544 + 131072 + 65536);  // + 344,064 B
  int*    bar  = (int*)(ws + 1065216);                     // barrier counters

  fused_all<<<NBLK, 256, 0, stream>>>(s_i, Wa, Ws, Wst, act,
                                      coef, Wws, Mws, Wt, bar, (float*)d_out);
}

// Round 8
// 144.315 us; speedup vs baseline: 1.2627x; 1.0266x over previous
//
#include <hip/hip_runtime.h>

#define TT    2048
#define SS    512
#define NB    16
#define EPEN  0.60653065971263342f   // exp(-0.5)
#define NCHUNK 64
#define CLEN   32
#define NBLK  65
#define MAGIC 0x5ca1ab1e

typedef __attribute__((ext_vector_type(4))) float  floatx4;
typedef __attribute__((ext_vector_type(8))) short  bf16x8;

__device__ __forceinline__ ushort f2bf(float x) {   // RNE fp32 -> bf16
  unsigned u = __float_as_uint(x);
  u += 0x7fffu + ((u >> 16) & 1u);
  return (ushort)(u >> 16);
}

template <int N>
__device__ __forceinline__ float ror_add(float v) {
  int r = __builtin_amdgcn_mov_dpp(__float_as_int(v), 0x120 + N, 0xF, 0xF, true);
  return v + __int_as_float(r);
}
__device__ __forceinline__ float reduce16(float v) {
  v = ror_add<8>(v); v = ror_add<4>(v); v = ror_add<2>(v); v = ror_add<1>(v);
  return v;
}

__device__ __forceinline__ int poll(int* p) {
  return __hip_atomic_fetch_add(p, 0, __ATOMIC_RELAXED, __HIP_MEMORY_SCOPE_AGENT);
}
__device__ __forceinline__ void arrive(int* p) {
  __builtin_amdgcn_fence(__ATOMIC_RELEASE, "agent");
  __hip_atomic_fetch_add(p, 1, __ATOMIC_RELAXED, __HIP_MEMORY_SCOPE_AGENT);
}
__device__ __forceinline__ void wait_for(int* p, int target) {
  while (poll(p) < target) __builtin_amdgcn_s_sleep(2);
  __builtin_amdgcn_fence(__ATOMIC_ACQUIRE, "agent");
}

__global__ __launch_bounds__(256, 1) void fused_all(
    const float* __restrict__ s_i,
    const float* __restrict__ Wa,
    const float* __restrict__ Ws,
    const float* __restrict__ Wst,
    const int*   __restrict__ actions,
    float4* __restrict__ coef, float* __restrict__ Wws,
    float* __restrict__ Mws,   ushort* __restrict__ Wt,
    int* __restrict__ bar,     float* __restrict__ out)
{
  __shared__ float lg[32][344];            // proj logits (44 KB)
  __shared__ float pk[NCHUNK][16];
  __shared__ int   Ee[NCHUNK];
  __shared__ float racc[17];
  __shared__ int   kacc[16];

  const int tid = threadIdx.x;
  const int bid = blockIdx.x;

  // ---- init: block 0 zeroes barrier counters, publishes MAGIC ----
  if (bid == 0 && tid == 0) {
    #pragma unroll
    for (int i = 0; i < 4; ++i)
      __hip_atomic_store(&bar[i], 0, __ATOMIC_RELAXED, __HIP_MEMORY_SCOPE_AGENT);
    __builtin_amdgcn_fence(__ATOMIC_RELEASE, "agent");
    __hip_atomic_store(&bar[7], MAGIC, __ATOMIC_RELAXED, __HIP_MEMORY_SCOPE_AGENT);
  }

  // ---- phase A: W -> transposed bf16 Wt[col][k], 8-k strips ----
  for (int sid = bid * 256 + tid; sid < 336 * 64; sid += NBLK * 256) {
    int col = sid >> 6, kk = (sid & 63) << 3;
    const float* src; int ld, cc;
    if (col < 288)      { src = Wa;  ld = 288; cc = col; }
    else if (col < 320) { src = Ws;  ld = 32;  cc = col - 288; }
    else                { src = Wst; ld = 16;  cc = col - 320; }
    uint4 pkd;
    uint h0 = f2bf(src[(size_t)(kk+0)*ld+cc]) | ((uint)f2bf(src[(size_t)(kk+1)*ld+cc]) << 16);
    uint h1 = f2bf(src[(size_t)(kk+2)*ld+cc]) | ((uint)f2bf(src[(size_t)(kk+3)*ld+cc]) << 16);
    uint h2 = f2bf(src[(size_t)(kk+4)*ld+cc]) | ((uint)f2bf(src[(size_t)(kk+5)*ld+cc]) << 16);
    uint h3 = f2bf(src[(size_t)(kk+6)*ld+cc]) | ((uint)f2bf(src[(size_t)(kk+7)*ld+cc]) << 16);
    pkd.x = h0; pkd.y = h1; pkd.z = h2; pkd.w = h3;
    *(uint4*)(Wt + (size_t)col * 512 + kk) = pkd;
  }

  // handshake (bar counters valid), then barrier 0: Wt ready (all 65 need it)
  if (tid == 0) {
    while (poll(&bar[7]) != (int)MAGIC) __builtin_amdgcn_s_sleep(2);
    __builtin_amdgcn_fence(__ATOMIC_ACQUIRE, "agent");
    arrive(&bar[0]);
    wait_for(&bar[0], NBLK);
  }
  __syncthreads();

  // ---- phase B: MFMA proj + softmax -> coef (32 rows/block) ----
  {
    const int wave = tid >> 6, lane = tid & 63;
    const int q = lane >> 4, rc = lane & 15;
    const int row0 = bid * 32;
    const int mbase  = (wave >> 1) * 16;
    const int ntile0 = (wave & 1) * 11;
    const int ntiles = (wave & 1) ? 10 : 11;

    int arow = row0 + mbase + rc; if (arow > TT) arow = TT;
    const float*  aptr  = s_i + (size_t)arow * SS + q * 8;
    const ushort* bbase = Wt + (size_t)(ntile0 * 16 + rc) * 512 + q * 8;

    floatx4 acc[11];
    #pragma unroll
    for (int n = 0; n < 11; ++n) acc[n] = (floatx4)(0.f);

    #pragma unroll 2
    for (int kt = 0; kt < 16; ++kt) {
      float4 a0 = *(const float4*)(aptr + kt * 32);
      float4 a1 = *(const float4*)(aptr + kt * 32 + 4);
      bf16x8 af;
      af[0] = (short)f2bf(a0.x); af[1] = (short)f2bf(a0.y);
      af[2] = (short)f2bf(a0.z); af[3] = (short)f2bf(a0.w);
      af[4] = (short)f2bf(a1.x); af[5] = (short)f2bf(a1.y);
      af[6] = (short)f2bf(a1.z); af[7] = (short)f2bf(a1.w);
      #pragma unroll
      for (int n = 0; n < 11; ++n) {
        if (n < ntiles) {
          bf16x8 bf = *(const bf16x8*)(bbase + (size_t)n * 16 * 512 + kt * 32);
          acc[n] = __builtin_amdgcn_mfma_f32_16x16x32_bf16(af, bf, acc[n], 0, 0, 0);
        }
      }
    }

    #pragma unroll
    for (int n = 0; n < 11; ++n) {
      if (n < ntiles) {
        int colt = ntile0 + n;
        #pragma unroll
        for (int reg = 0; reg < 4; ++reg)
          lg[mbase + q * 4 + reg][colt * 16 + rc] = acc[n][reg];
      }
    }
    __syncthreads();

    #pragma unroll
    for (int h = 0; h < 2; ++h) {
      const int r = h * 16 + (tid >> 4), b = tid & 15;
      const int row = row0 + r;
      if (row < TT) {
        float m = -3.4e38f;
        #pragma unroll
        for (int a = 0; a < 18; ++a) m = fmaxf(m, lg[r][b * 18 + a]);
        float sum = 0.f;
        #pragma unroll
        for (int a = 0; a < 18; ++a) sum += __expf(lg[r][b * 18 + a] - m);
        int act = actions[row];
        float aprob = __expf(lg[r][b * 18 + act] - m) / sum;

        float x0 = lg[r][288 + 2 * b], x1 = lg[r][288 + 2 * b + 1];
        float mm = fmaxf(x0, x1);
        float e0 = __expf(x0 - mm), e1 = __expf(x1 - mm);
        float inv = 1.f / (e0 + e1);

        float ms = -3.4e38f;
        #pragma unroll
        for (int j = 0; j < 16; ++j) ms = fmaxf(ms, lg[r][320 + j]);
        float ssum = 0.f;
        #pragma unroll
        for (int j = 0; j < 16; ++j) ssum += __expf(lg[r][320 + j] - ms);
        float stp = __expf(lg[r][320 + b] - ms) / ssum;

        coef[(size_t)row * NB + b] = make_float4(e0 * inv, e1 * inv, stp, aprob);
      } else if (row == TT) {
        float x0 = lg[r][288 + 2 * b], x1 = lg[r][288 + 2 * b + 1];
        float mm = fmaxf(x0, x1);
        float e0 = __expf(x0 - mm), e1 = __expf(x1 - mm);
        coef[(size_t)TT * NB + b] = make_float4(1.f, 0.f, 0.f, e0 / (e0 + e1));
      }
    }
  }

  // barrier 1: coef ready. Blocks >=16 arrive and EXIT (no further role).
  __syncthreads();
  if (bid >= 16) {
    if (tid == 0) arrive(&bar[1]);
    return;
  }
  if (tid == 0) { arrive(&bar[1]); wait_for(&bar[1], NBLK); }
  __syncthreads();

  // ---- phase C: pass1 (blocks 0..15, 4 chunks each) — NO double-buffer, ---
  // ---- single-step CF[16] working set (~100 VGPR live, no spill) ---------
  if (tid < 64) {
    const int k = bid * 4 + (tid >> 4);
    const int c = tid & 15;
    const int i0 = k * CLEN + 1;
    float G[16];
    #pragma unroll
    for (int r = 0; r < 16; ++r) G[r] = (r == c) ? 1.f : 0.f;

    #pragma unroll 1
    for (int j = 0; j < CLEN; ++j) {
      float4 CF[16];
      #pragma unroll
      for (int r = 0; r < 16; ++r) CF[r] = coef[(size_t)(i0 + j) * 16 + r];

      float ta = 0.f, tb = 0.f, tc2 = 0.f, td = 0.f;
      #pragma unroll
      for (int r = 0; r < 4; ++r) {
        ta  = fmaf(CF[r].y,      G[r],      ta);
        tb  = fmaf(CF[r + 4].y,  G[r + 4],  tb);
        tc2 = fmaf(CF[r + 8].y,  G[r + 8],  tc2);
        td  = fmaf(CF[r + 12].y, G[r + 12], td);
      }
      float et = EPEN * ((ta + tb) + (tc2 + td));
      #pragma unroll
      for (int r = 0; r < 16; ++r)
        G[r] = fmaf(CF[r].x, G[r], CF[r].z * et);
      float wa = 0.f, wb = 0.f, wc2 = 0.f, wd = 0.f;
      #pragma unroll
      for (int r = 0; r < 4; ++r) {
        wa  = fmaf(CF[r].w,      G[r],      wa);
        wb  = fmaf(CF[r + 4].w,  G[r + 4],  wb);
        wc2 = fmaf(CF[r + 8].w,  G[r + 8],  wc2);
        wd  = fmaf(CF[r + 12].w, G[r + 12], wd);
      }
      Wws[(size_t)(k * CLEN + j) * 16 + c] = (wa + wb) + (wc2 + wd);
    }

    #pragma unroll
    for (int rr = 0; rr < 4; ++rr) {
      float4 v = make_float4(G[rr * 4], G[rr * 4 + 1], G[rr * 4 + 2], G[rr * 4 + 3]);
      *(float4*)(Mws + k * 256 + c * 16 + rr * 4) = v;   // col-major per chunk
    }
  }

  // barrier 2 (16 blocks): blocks 1..15 arrive and EXIT; block 0 spins.
  __syncthreads();
  if (bid != 0) {
    if (tid == 0) arrive(&bar[2]);
    return;
  }
  if (tid == 0) { arrive(&bar[2]); wait_for(&bar[2], 16); }
  __syncthreads();

  // ---- phase D (block 0 only): 1-wave chunk walk ----
  if (tid < 64) {
    const int g = tid >> 4, cw = tid & 15;
    float4 c0 = coef[cw];
    float p = c0.z;
    float U0 = reduce16(c0.w * p);
    if (tid == 0) { racc[16] = __logf(U0); Ee[0] = 0; }
    if (g == 0) pk[0][cw] = p;
    int Ecum = 0;

    float4 mcur  = *(const float4*)(Mws + 0 * 256 + cw * 16 + g * 4);
    float4 mnext = *(const float4*)(Mws + 1 * 256 + cw * 16 + g * 4);
    for (int k = 0; k < NCHUNK; ++k) {
      float4 mc = mcur; mcur = mnext;
      if (k + 2 < NCHUNK)
        mnext = *(const float4*)(Mws + (size_t)(k + 2) * 256 + cw * 16 + g * 4);
      float y0 = reduce16(mc.x * p);
      float y1 = reduce16(mc.y * p);
      float y2 = reduce16(mc.z * p);
      float y3 = reduce16(mc.w * p);
      int sel = cw & 3;
      float z = (sel == 0) ? y0 : (sel == 1) ? y1 : (sel == 2) ? y2 : y3;
      int src = (((cw >> 2) * 16 + cw) << 2);
      float pn = __int_as_float(
          __builtin_amdgcn_ds_bpermute(src, __float_as_int(z)));
      int bits = __builtin_amdgcn_readfirstlane(__float_as_int(pn));
      int eb = (bits >> 23) & 255;
      Ecum += eb - 127;
      p = pn * __int_as_float((254 - eb) << 23);   // * 2^{-(eb-127)}, exact
      if (k + 1 < NCHUNK) {
        if (g == 0) pk[k + 1][cw] = p;
        if (tid == 0) Ee[k + 1] = Ecum;
      }
    }
  }
  __syncthreads();

  // ---- terms: 16 groups x 4 chunks x 32 steps ----
  {
    const int gg = tid >> 4, c = tid & 15;
    float acc = 0.f;
    int klocal = 0;
    #pragma unroll
    for (int h = 0; h < 4; ++h) {
      const int k = gg * 4 + h;
      const float pc = pk[k][c];
      klocal += CLEN * Ee[k];
      #pragma unroll 8
      for (int j = 0; j < CLEN; ++j) {
        float w = Wws[(size_t)(k * CLEN + j) * 16 + c];
        float U = reduce16(w * pc);
        acc += __logf(U);
      }
    }
    if (c == 0) { racc[gg] = acc; kacc[gg] = klocal; }
  }
  __syncthreads();
  if (tid == 0) {
    double s = (double)racc[16];
    long long K = 0;
    #pragma unroll
    for (int i = 0; i < 16; ++i) { s += (double)racc[i]; K += (long long)kacc[i]; }
    out[0] = (float)(s + 0.6931471805599453 * (double)K);
  }
}

extern "C" void kernel_launch(void* const* d_in, const int* in_sizes, int n_in,
                              void* d_out, int out_size, void* d_ws, size_t ws_size,
                              hipStream_t stream) {
  const float* s_i = (const float*)d_in[0];
  const float* Wa  = (const float*)d_in[1];
  const float* Ws  = (const float*)d_in[2];
  const float* Wst = (const float*)d_in[3];
  const int*   act = (const int*)d_in[4];

  char* ws = (char*)d_ws;
  float4* coef = (float4*)ws;                              //   524,544 B
  float*  Wws  = (float*)(ws + 524544);                    // + 131,072 B
  float*  Mws  = (float*)(ws + 524544 + 131072);           // +  65,536 B
  ushort* Wt   = (ushort*)(ws + 524544 + 131072 + 65536);  // + 344,064 B
  int*    bar  = (int*)(ws + 1065216);                     // barrier counters

  fused_all<<<NBLK, 256, 0, stream>>>(s_i, Wa, Ws, Wst, act,
                                      coef, Wws, Mws, Wt, bar, (float*)d_out);
}